// Round 7
// baseline (119.582 us; speedup 1.0000x reference)
//
#include <hip/hip_runtime.h>

// RecurrentDiscriminator round 7 = round-5 structure + asm-forced v_dot2_f32_f16.
// Hypothesis: __builtin_amdgcn_fdot2 path scalarized to cvt+fma (6 instrs per
// dot2, ~1200 extra instrs/step) -> 3750 cyc/step. Forcing the real VOP3P
// dot2 should cut issue count ~3x.
// - W1 resident f16x2 in ~150 arch VGPRs (pinned).
// - W2/W3 (100) + accInit (10) in AGPRs; pure-asm reads (schedulable).
// - Single-step-ahead obs prefetch, no sched_barrier.

#define NB   65536
#define NS   64
#define OBSD 20
#define NH   10

typedef __fp16 f16x2 __attribute__((ext_vector_type(2)));

#define KEEP(x) asm volatile("" : "+v"(x))

__device__ __forceinline__ float ftanh(float x) {
    float e = __builtin_amdgcn_exp2f(x * 2.885390081777927f);  // 2*log2(e)
    float r = __builtin_amdgcn_rcpf(1.0f + e);
    return fmaf(-2.0f, r, 1.0f);
}

__device__ __forceinline__ f16x2 pk(float a, float b) {
    return __builtin_amdgcn_cvt_pkrtz(a, b);
}

// Forced VOP3P dot2: d = a.x*b.x + a.y*b.y + c, f32 accumulate.
__device__ __forceinline__ float dot2(f16x2 a, f16x2 b, float c) {
    float d;
    asm("v_dot2_f32_f16 %0, %1, %2, %3" : "=v"(d) : "v"(a), "v"(b), "v"(c));
    return d;
}

__device__ __forceinline__ void agpr_put(float& slot, float v) {
    asm volatile("v_accvgpr_write_b32 %0, %1" : "=a"(slot) : "v"(v));
}
// pure (non-volatile): scheduler may hoist/interleave these
__device__ __forceinline__ float agpr_getf(const float& slot) {
    float f;
    asm("v_accvgpr_read_b32 %0, %1" : "=v"(f) : "a"(slot));
    return f;
}
__device__ __forceinline__ f16x2 agpr_geth(const float& slot) {
    float f;
    asm("v_accvgpr_read_b32 %0, %1" : "=v"(f) : "a"(slot));
    return __builtin_bit_cast(f16x2, f);
}

__global__ __launch_bounds__(256, 1)
void rd_fwd(const float* __restrict__ states, const float* __restrict__ actions,
            const float* __restrict__ W1, const float* __restrict__ b1,
            const float* __restrict__ W2, const float* __restrict__ b2,
            const float* __restrict__ W3, const float* __restrict__ b3,
            const float* __restrict__ Wg1, const float* __restrict__ bg1,
            const float* __restrict__ Wg2, const float* __restrict__ bg2,
            float* __restrict__ out)
{
    const int b = blockIdx.x * blockDim.x + threadIdx.x;
    const float* __restrict__ row = states + (size_t)b * (NS * OBSD);

    // ---- W1 pair-rows 0..14 resident f16x2, pinned ----
    f16x2 w1p[15 * NH];
#pragma unroll
    for (int p = 0; p < 15; ++p)
#pragma unroll
        for (int o = 0; o < NH; ++o)
            w1p[p * NH + o] = pk(W1[(2 * p) * NH + o], W1[(2 * p + 1) * NH + o]);
#pragma unroll
    for (int i = 0; i < 15 * NH; ++i) KEEP(w1p[i]);

    // ---- accInit = b1 + a0*W1row30 + a1*W1row31 -> AGPR ----
    const float a0 = actions[2 * b];
    const float a1 = actions[2 * b + 1];
    float accInit_a[NH];
#pragma unroll
    for (int o = 0; o < NH; ++o) {
        float v = fmaf(a0, W1[30 * NH + o], fmaf(a1, W1[31 * NH + o], b1[o]));
        agpr_put(accInit_a[o], v);
    }

    // ---- W2/W3 packed f16x2 -> AGPRs ----
    float aw2[5 * NH], aw3[5 * NH];
#pragma unroll
    for (int p = 0; p < 5; ++p)
#pragma unroll
        for (int o = 0; o < NH; ++o) {
            agpr_put(aw2[p * NH + o],
                     __builtin_bit_cast(float, pk(W2[(2 * p) * NH + o], W2[(2 * p + 1) * NH + o])));
            agpr_put(aw3[p * NH + o],
                     __builtin_bit_cast(float, pk(W3[(2 * p) * NH + o], W3[(2 * p + 1) * NH + o])));
        }

    float b2r[NH], b3r[NH];
#pragma unroll
    for (int o = 0; o < NH; ++o) { b2r[o] = b2[o]; b3r[o] = b3[o]; }

    float st[NH];
#pragma unroll
    for (int o = 0; o < NH; ++o) st[o] = 0.0f;

    // obs prefetch for step 0
    float4 n0 = *(const float4*)(row + 0);
    float4 n1 = *(const float4*)(row + 4);
    float4 n2 = *(const float4*)(row + 8);
    float4 n3 = *(const float4*)(row + 12);
    float4 n4 = *(const float4*)(row + 16);

#pragma unroll 1
    for (int s = 0; s < NS; ++s) {
        // consume prefetched obs, pack to f16x2
        f16x2 obsP[10];
        obsP[0] = pk(n0.x, n0.y); obsP[1] = pk(n0.z, n0.w);
        obsP[2] = pk(n1.x, n1.y); obsP[3] = pk(n1.z, n1.w);
        obsP[4] = pk(n2.x, n2.y); obsP[5] = pk(n2.z, n2.w);
        obsP[6] = pk(n3.x, n3.y); obsP[7] = pk(n3.z, n3.w);
        obsP[8] = pk(n4.x, n4.y); obsP[9] = pk(n4.z, n4.w);

        // issue next step's loads (covered by this step's compute)
        {
            const int sn = (s < NS - 1) ? s + 1 : s;
            const float* pf = row + sn * OBSD;
            n0 = *(const float4*)(pf + 0);
            n1 = *(const float4*)(pf + 4);
            n2 = *(const float4*)(pf + 8);
            n3 = *(const float4*)(pf + 12);
            n4 = *(const float4*)(pf + 16);
        }

        f16x2 stp[5];
#pragma unroll
        for (int p = 0; p < 5; ++p) stp[p] = pk(st[2 * p], st[2 * p + 1]);

        // ---- layer 1 ----
        float acc[NH];
#pragma unroll
        for (int o = 0; o < NH; ++o) acc[o] = agpr_getf(accInit_a[o]);
#pragma unroll
        for (int p = 0; p < 5; ++p)
#pragma unroll
            for (int o = 0; o < NH; ++o) acc[o] = dot2(stp[p], w1p[p * NH + o], acc[o]);
#pragma unroll
        for (int p = 0; p < 10; ++p)
#pragma unroll
            for (int o = 0; o < NH; ++o) acc[o] = dot2(obsP[p], w1p[(5 + p) * NH + o], acc[o]);
#pragma unroll
        for (int o = 0; o < NH; ++o) acc[o] = ftanh(acc[o]);

        f16x2 h1p[5];
#pragma unroll
        for (int p = 0; p < 5; ++p) h1p[p] = pk(acc[2 * p], acc[2 * p + 1]);

        // ---- layer 2 (W2 from AGPR) ----
        float acc2[NH];
#pragma unroll
        for (int o = 0; o < NH; ++o) acc2[o] = b2r[o];
#pragma unroll
        for (int p = 0; p < 5; ++p)
#pragma unroll
            for (int o = 0; o < NH; ++o)
                acc2[o] = dot2(h1p[p], agpr_geth(aw2[p * NH + o]), acc2[o]);
#pragma unroll
        for (int o = 0; o < NH; ++o) acc2[o] = ftanh(acc2[o]);

        f16x2 h2p[5];
#pragma unroll
        for (int p = 0; p < 5; ++p) h2p[p] = pk(acc2[2 * p], acc2[2 * p + 1]);

        // ---- layer 3 (W3 from AGPR) ----
#pragma unroll
        for (int o = 0; o < NH; ++o) st[o] += b3r[o];
#pragma unroll
        for (int p = 0; p < 5; ++p)
#pragma unroll
            for (int o = 0; o < NH; ++o)
                st[o] = dot2(h2p[p], agpr_geth(aw3[p * NH + o]), st[o]);
    }

    // ---- head (once, f32, uniform weights) ----
    float g[NH];
#pragma unroll
    for (int o = 0; o < NH; ++o) {
        float a = bg1[o];
#pragma unroll
        for (int i = 0; i < NH; ++i) a = fmaf(st[i], Wg1[i * NH + o], a);
        g[o] = ftanh(a);
    }
    float r = bg2[0];
#pragma unroll
    for (int o = 0; o < NH; ++o) r = fmaf(g[o], Wg2[o], r);
    out[b] = r;
}

extern "C" void kernel_launch(void* const* d_in, const int* in_sizes, int n_in,
                              void* d_out, int out_size, void* d_ws, size_t ws_size,
                              hipStream_t stream) {
    const float* states  = (const float*)d_in[0];
    const float* actions = (const float*)d_in[1];
    const float* W1  = (const float*)d_in[2];
    const float* b1  = (const float*)d_in[3];
    const float* W2  = (const float*)d_in[4];
    const float* b2  = (const float*)d_in[5];
    const float* W3  = (const float*)d_in[6];
    const float* b3  = (const float*)d_in[7];
    const float* Wg1 = (const float*)d_in[8];
    const float* bg1 = (const float*)d_in[9];
    const float* Wg2 = (const float*)d_in[10];
    const float* bg2 = (const float*)d_in[11];
    float* out = (float*)d_out;

    rd_fwd<<<NB / 256, 256, 0, stream>>>(states, actions, W1, b1, W2, b2,
                                         W3, b3, Wg1, bg1, Wg2, bg2, out);
}

// Round 8
// 103.562 us; speedup vs baseline: 1.1547x; 1.1547x over previous
//
#include <hip/hip_runtime.h>

// RecurrentDiscriminator round 8: 2 lanes per element -> 2 waves/SIMD.
// Lane parity h owns output cols [5h, 5h+5) of every layer. Cross-half
// activation exchange via DPP quad_perm(1,0,3,2) (lane^1), pure VALU.
// Per-lane weights: W1-half 75 f16x2 + W2/W3-half 25 each, all arch-VGPR
// resident. Builtin fdot2 (R7 showed asm dot2 adds mov per op). R5 prefetch.

#define NB   65536
#define NS   64
#define OBSD 20
#define NH   10

typedef __fp16 f16x2 __attribute__((ext_vector_type(2)));

#define KEEP(x) asm volatile("" : "+v"(x))

__device__ __forceinline__ float ftanh(float x) {
    float e = __builtin_amdgcn_exp2f(x * 2.885390081777927f);  // 2*log2(e)
    float r = __builtin_amdgcn_rcpf(1.0f + e);
    return fmaf(-2.0f, r, 1.0f);
}

__device__ __forceinline__ f16x2 pk(float a, float b) {
    return __builtin_amdgcn_cvt_pkrtz(a, b);
}

#if __has_builtin(__builtin_amdgcn_fdot2)
__device__ __forceinline__ float dot2(f16x2 a, f16x2 b, float c) {
    return __builtin_amdgcn_fdot2(a, b, c, false);
}
#else
__device__ __forceinline__ float dot2(f16x2 a, f16x2 b, float c) {
    return fmaf((float)a[0], (float)b[0], fmaf((float)a[1], (float)b[1], c));
}
#endif

// partner lane (lane^1) value via DPP quad_perm(1,0,3,2) = ctrl 0xB1
__device__ __forceinline__ float xchg(float x) {
    int i = __builtin_bit_cast(int, x);
    int j = __builtin_amdgcn_mov_dpp(i, 0xB1, 0xF, 0xF, true);
    return __builtin_bit_cast(float, j);
}

// v[5] = my half's f32 values (cols 5h..5h+4). Produce the full 10-vector
// as 5 packed f16x2 pairs (0,1),(2,3),(4,5),(6,7),(8,9) on BOTH lanes.
__device__ __forceinline__ void merge5(const float v[5], bool h, f16x2 outp[5]) {
    float p0 = xchg(v[0]), p1 = xchg(v[1]), p2 = xchg(v[2]),
          p3 = xchg(v[3]), p4 = xchg(v[4]);
    float lo0 = h ? p0 : v[0], lo1 = h ? p1 : v[1], lo2 = h ? p2 : v[2],
          lo3 = h ? p3 : v[3], lo4 = h ? p4 : v[4];
    float hi0 = h ? v[0] : p0, hi1 = h ? v[1] : p1, hi2 = h ? v[2] : p2,
          hi3 = h ? v[3] : p3, hi4 = h ? v[4] : p4;
    outp[0] = pk(lo0, lo1); outp[1] = pk(lo2, lo3); outp[2] = pk(lo4, hi0);
    outp[3] = pk(hi1, hi2); outp[4] = pk(hi3, hi4);
}

__global__ __launch_bounds__(256, 2)
void rd_fwd(const float* __restrict__ states, const float* __restrict__ actions,
            const float* __restrict__ W1, const float* __restrict__ b1,
            const float* __restrict__ W2, const float* __restrict__ b2,
            const float* __restrict__ W3, const float* __restrict__ b3,
            const float* __restrict__ Wg1, const float* __restrict__ bg1,
            const float* __restrict__ Wg2, const float* __restrict__ bg2,
            float* __restrict__ out)
{
    const int t = blockIdx.x * blockDim.x + threadIdx.x;  // 0..2*NB-1
    const int e = t >> 1;          // element
    const bool h = t & 1;          // output-half: cols c0..c0+4
    const int c0 = h ? 5 : 0;
    const float* __restrict__ row = states + (size_t)e * (NS * OBSD);

    // ---- per-lane weight halves (once; W1/W2/W3 are tiny, L2-resident) ----
    f16x2 w1h[15 * 5];             // pair-rows 0..14 (x rows 0..29), my 5 cols
#pragma unroll
    for (int p = 0; p < 15; ++p)
#pragma unroll
        for (int j = 0; j < 5; ++j)
            w1h[p * 5 + j] = pk(W1[(2 * p) * NH + c0 + j],
                                W1[(2 * p + 1) * NH + c0 + j]);
#pragma unroll
    for (int i = 0; i < 75; ++i) KEEP(w1h[i]);

    f16x2 w2h[25], w3h[25];
#pragma unroll
    for (int p = 0; p < 5; ++p)
#pragma unroll
        for (int j = 0; j < 5; ++j) {
            w2h[p * 5 + j] = pk(W2[(2 * p) * NH + c0 + j],
                                W2[(2 * p + 1) * NH + c0 + j]);
            w3h[p * 5 + j] = pk(W3[(2 * p) * NH + c0 + j],
                                W3[(2 * p + 1) * NH + c0 + j]);
        }
#pragma unroll
    for (int i = 0; i < 25; ++i) { KEEP(w2h[i]); KEEP(w3h[i]); }

    // accInit = b1 + a0*W1row30 + a1*W1row31 (my cols), step-invariant
    const float a0 = actions[2 * e];
    const float a1 = actions[2 * e + 1];
    float accI[5], b2h[5], b3h[5];
#pragma unroll
    for (int j = 0; j < 5; ++j) {
        accI[j] = fmaf(a0, W1[30 * NH + c0 + j],
                  fmaf(a1, W1[31 * NH + c0 + j], b1[c0 + j]));
        b2h[j] = b2[c0 + j];
        b3h[j] = b3[c0 + j];
    }

    float sth[5];
#pragma unroll
    for (int j = 0; j < 5; ++j) sth[j] = 0.0f;

    // obs prefetch for step 0 (both lanes of the pair load the same line)
    float4 n0 = *(const float4*)(row + 0);
    float4 n1 = *(const float4*)(row + 4);
    float4 n2 = *(const float4*)(row + 8);
    float4 n3 = *(const float4*)(row + 12);
    float4 n4 = *(const float4*)(row + 16);

#pragma unroll 1
    for (int s = 0; s < NS; ++s) {
        f16x2 obsP[10];
        obsP[0] = pk(n0.x, n0.y); obsP[1] = pk(n0.z, n0.w);
        obsP[2] = pk(n1.x, n1.y); obsP[3] = pk(n1.z, n1.w);
        obsP[4] = pk(n2.x, n2.y); obsP[5] = pk(n2.z, n2.w);
        obsP[6] = pk(n3.x, n3.y); obsP[7] = pk(n3.z, n3.w);
        obsP[8] = pk(n4.x, n4.y); obsP[9] = pk(n4.z, n4.w);

        // issue next step's loads (covered by this step's compute)
        {
            const int sn = (s < NS - 1) ? s + 1 : s;
            const float* pf = row + sn * OBSD;
            n0 = *(const float4*)(pf + 0);
            n1 = *(const float4*)(pf + 4);
            n2 = *(const float4*)(pf + 8);
            n3 = *(const float4*)(pf + 12);
            n4 = *(const float4*)(pf + 16);
        }

        // ---- layer 1 (75 dot2): x = [st(10), obs(20)] ----
        f16x2 stp[5];
        merge5(sth, h, stp);
        float acc[5];
#pragma unroll
        for (int j = 0; j < 5; ++j) acc[j] = accI[j];
#pragma unroll
        for (int p = 0; p < 5; ++p)
#pragma unroll
            for (int j = 0; j < 5; ++j)
                acc[j] = dot2(stp[p], w1h[p * 5 + j], acc[j]);
#pragma unroll
        for (int q = 0; q < 10; ++q)
#pragma unroll
            for (int j = 0; j < 5; ++j)
                acc[j] = dot2(obsP[q], w1h[(5 + q) * 5 + j], acc[j]);
#pragma unroll
        for (int j = 0; j < 5; ++j) acc[j] = ftanh(acc[j]);

        // ---- layer 2 (25 dot2) ----
        f16x2 h1p[5];
        merge5(acc, h, h1p);
        float acc2[5];
#pragma unroll
        for (int j = 0; j < 5; ++j) acc2[j] = b2h[j];
#pragma unroll
        for (int p = 0; p < 5; ++p)
#pragma unroll
            for (int j = 0; j < 5; ++j)
                acc2[j] = dot2(h1p[p], w2h[p * 5 + j], acc2[j]);
#pragma unroll
        for (int j = 0; j < 5; ++j) acc2[j] = ftanh(acc2[j]);

        // ---- layer 3 (25 dot2): st += h2 @ W3 + b3 ----
        f16x2 h2p[5];
        merge5(acc2, h, h2p);
#pragma unroll
        for (int j = 0; j < 5; ++j) sth[j] += b3h[j];
#pragma unroll
        for (int p = 0; p < 5; ++p)
#pragma unroll
            for (int j = 0; j < 5; ++j)
                sth[j] = dot2(h2p[p], w3h[p * 5 + j], sth[j]);
    }

    // ---- head (once, f32) ----
    float p5[5];
#pragma unroll
    for (int j = 0; j < 5; ++j) p5[j] = xchg(sth[j]);
    float stA[10];
#pragma unroll
    for (int j = 0; j < 5; ++j) {
        stA[j]     = h ? p5[j] : sth[j];
        stA[5 + j] = h ? sth[j] : p5[j];
    }
    float r = 0.0f;
#pragma unroll
    for (int j = 0; j < 5; ++j) {
        float a = bg1[c0 + j];
#pragma unroll
        for (int i = 0; i < NH; ++i) a = fmaf(stA[i], Wg1[i * NH + c0 + j], a);
        r = fmaf(ftanh(a), Wg2[c0 + j], r);
    }
    r += xchg(r);                   // sum both halves (before divergence)
    if (!h) out[e] = r + bg2[0];
}

extern "C" void kernel_launch(void* const* d_in, const int* in_sizes, int n_in,
                              void* d_out, int out_size, void* d_ws, size_t ws_size,
                              hipStream_t stream) {
    const float* states  = (const float*)d_in[0];
    const float* actions = (const float*)d_in[1];
    const float* W1  = (const float*)d_in[2];
    const float* b1  = (const float*)d_in[3];
    const float* W2  = (const float*)d_in[4];
    const float* b2  = (const float*)d_in[5];
    const float* W3  = (const float*)d_in[6];
    const float* b3  = (const float*)d_in[7];
    const float* Wg1 = (const float*)d_in[8];
    const float* bg1 = (const float*)d_in[9];
    const float* Wg2 = (const float*)d_in[10];
    const float* bg2 = (const float*)d_in[11];
    float* out = (float*)d_out;

    rd_fwd<<<(NB * 2) / 256, 256, 0, stream>>>(states, actions, W1, b1, W2, b2,
                                               W3, b3, Wg1, bg1, Wg2, bg2, out);
}